// Round 1
// baseline (323.102 us; speedup 1.0000x reference)
//
#include <hip/hip_runtime.h>

#define DIM 1024
#define NH 16
#define NKV 4
#define HD 64
#define INTER 2688
#define BB 2
#define NN 2048
#define MM (BB*NN)

typedef __attribute__((ext_vector_type(4))) float f32x4;
typedef __attribute__((ext_vector_type(8))) short short8;

__device__ __forceinline__ unsigned short f2bf(float f) {
  union { float f; unsigned u; } v; v.f = f;
  unsigned r = v.u + 0x7fffu + ((v.u >> 16) & 1u);
  return (unsigned short)(r >> 16);
}

// ---------------- transpose fp32 [K][Nc] -> bf16 [Nc][K] ----------------
__global__ void transpose_k(const float* __restrict__ W, unsigned short* __restrict__ Wt,
                            int K, int Nc) {
  __shared__ float tile[32][33];
  int n0 = blockIdx.x * 32, k0 = blockIdx.y * 32;
  int tx = threadIdx.x & 31, ty = threadIdx.x >> 5;
#pragma unroll
  for (int i = 0; i < 32; i += 8)
    tile[ty + i][tx] = W[(size_t)(k0 + ty + i) * Nc + n0 + tx];
  __syncthreads();
#pragma unroll
  for (int i = 0; i < 32; i += 8)
    Wt[(size_t)(n0 + ty + i) * K + k0 + tx] = f2bf(tile[tx][ty + i]);
}

// ---------------- RMSNorm: fp32 [rows][1024] -> bf16 ----------------
__global__ void rmsnorm_k(const float* __restrict__ x, const float* __restrict__ w,
                          unsigned short* __restrict__ h) {
  int row = blockIdx.x;
  int t = threadIdx.x;
  const float4* xr = (const float4*)(x + (size_t)row * DIM);
  float4 v = xr[t];
  float ss = v.x * v.x + v.y * v.y + v.z * v.z + v.w * v.w;
#pragma unroll
  for (int o = 1; o < 64; o <<= 1) ss += __shfl_xor(ss, o);
  __shared__ float ps[4];
  if ((t & 63) == 0) ps[t >> 6] = ss;
  __syncthreads();
  float r = rsqrtf((ps[0] + ps[1] + ps[2] + ps[3]) * (1.0f / DIM) + 1e-6f);
  const float4* wr = (const float4*)w;
  float4 wv = wr[t];
  ushort4 o4;
  o4.x = f2bf(v.x * r * wv.x);
  o4.y = f2bf(v.y * r * wv.y);
  o4.z = f2bf(v.z * r * wv.z);
  o4.w = f2bf(v.w * r * wv.w);
  *(ushort4*)(h + (size_t)row * DIM + t * 4) = o4;
}

// ---------------- GEMM: C[M][Nc] = A[M][K] @ Bt[Nc][K]^T (+res), fp32 out ----------------
// 128x128 tile, 4 waves (2x2), per-wave 64x64 = 4x4 frags of 16x16, BK=32.
#define LDA 56  // padded LDS row stride (elems); 112B, 16B-aligned, ~2-way banks
template <bool RES>
__global__ __launch_bounds__(256, 2) void gemm_f32(
    const unsigned short* __restrict__ A, const unsigned short* __restrict__ Bt,
    const float* __restrict__ res, float* __restrict__ C, int Nc, int K) {
  __shared__ __align__(16) unsigned short Asm[128 * LDA];
  __shared__ __align__(16) unsigned short Bsm[128 * LDA];
  int tid = threadIdx.x;
  int w = tid >> 6, l = tid & 63;
  int bm = blockIdx.y * 128, bn = blockIdx.x * 128;
  int wr = (w >> 1) * 64, wc = (w & 1) * 64;
  int srow = tid >> 2, scol = (tid & 3) * 8;

  const short8* gA0 = (const short8*)(A + (size_t)(bm + srow) * K + scol);
  const short8* gA1 = (const short8*)(A + (size_t)(bm + srow + 64) * K + scol);
  const short8* gB0 = (const short8*)(Bt + (size_t)(bn + srow) * K + scol);
  const short8* gB1 = (const short8*)(Bt + (size_t)(bn + srow + 64) * K + scol);

  f32x4 acc[4][4] = {};
  short8 ra0 = gA0[0], ra1 = gA1[0], rb0 = gB0[0], rb1 = gB1[0];
  int nsteps = K / 32;
  int kof = (l >> 4) * 8, c0 = l & 15;
  for (int s = 0; s < nsteps; ++s) {
    __syncthreads();
    *(short8*)&Asm[srow * LDA + scol] = ra0;
    *(short8*)&Asm[(srow + 64) * LDA + scol] = ra1;
    *(short8*)&Bsm[srow * LDA + scol] = rb0;
    *(short8*)&Bsm[(srow + 64) * LDA + scol] = rb1;
    __syncthreads();
    if (s + 1 < nsteps) {
      int ko = (s + 1) * 4;  // short8 units = 32 elems
      ra0 = gA0[ko]; ra1 = gA1[ko]; rb0 = gB0[ko]; rb1 = gB1[ko];
    }
    short8 af[4], bf[4];
#pragma unroll
    for (int m = 0; m < 4; m++)
      af[m] = *(const short8*)&Asm[(wr + m * 16 + c0) * LDA + kof];
#pragma unroll
    for (int n = 0; n < 4; n++)
      bf[n] = *(const short8*)&Bsm[(wc + n * 16 + c0) * LDA + kof];
#pragma unroll
    for (int m = 0; m < 4; m++)
#pragma unroll
      for (int n = 0; n < 4; n++)
        acc[m][n] = __builtin_amdgcn_mfma_f32_16x16x32_bf16(af[m], bf[n], acc[m][n], 0, 0, 0);
  }
  int g = l >> 4;
#pragma unroll
  for (int m = 0; m < 4; m++) {
#pragma unroll
    for (int i = 0; i < 4; i++) {
      int row = bm + wr + m * 16 + g * 4 + i;
#pragma unroll
      for (int n = 0; n < 4; n++) {
        int col = bn + wc + n * 16 + c0;
        float v = acc[m][n][i];
        if (RES) v += res[(size_t)row * Nc + col];
        C[(size_t)row * Nc + col] = v;
      }
    }
  }
}

// ---------------- fused FFN13: g = silu(A@W1t^T) * (A@W3t^T), bf16 out ----------------
// 128x64 tile, 4 waves (2x2), per-wave 64x32 = 4x2 frags, two B matrices.
__global__ __launch_bounds__(256, 2) void gemm_ffn13(
    const unsigned short* __restrict__ A, const unsigned short* __restrict__ B1t,
    const unsigned short* __restrict__ B3t, unsigned short* __restrict__ G,
    int Nc, int K) {
  __shared__ __align__(16) unsigned short Asm[128 * LDA];
  __shared__ __align__(16) unsigned short B1sm[64 * LDA];
  __shared__ __align__(16) unsigned short B3sm[64 * LDA];
  int tid = threadIdx.x;
  int w = tid >> 6, l = tid & 63;
  int bm = blockIdx.y * 128, bn = blockIdx.x * 64;
  int wr = (w >> 1) * 64, wc = (w & 1) * 32;
  int srow = tid >> 2, scol = (tid & 3) * 8;

  const short8* gA0 = (const short8*)(A + (size_t)(bm + srow) * K + scol);
  const short8* gA1 = (const short8*)(A + (size_t)(bm + srow + 64) * K + scol);
  const short8* gB1 = (const short8*)(B1t + (size_t)(bn + srow) * K + scol);
  const short8* gB3 = (const short8*)(B3t + (size_t)(bn + srow) * K + scol);

  f32x4 a1[4][2] = {};
  f32x4 a3[4][2] = {};
  short8 ra0 = gA0[0], ra1 = gA1[0], rb1 = gB1[0], rb3 = gB3[0];
  int nsteps = K / 32;
  int kof = (l >> 4) * 8, c0 = l & 15;
  for (int s = 0; s < nsteps; ++s) {
    __syncthreads();
    *(short8*)&Asm[srow * LDA + scol] = ra0;
    *(short8*)&Asm[(srow + 64) * LDA + scol] = ra1;
    *(short8*)&B1sm[srow * LDA + scol] = rb1;
    *(short8*)&B3sm[srow * LDA + scol] = rb3;
    __syncthreads();
    if (s + 1 < nsteps) {
      int ko = (s + 1) * 4;
      ra0 = gA0[ko]; ra1 = gA1[ko]; rb1 = gB1[ko]; rb3 = gB3[ko];
    }
    short8 af[4], b1f[2], b3f[2];
#pragma unroll
    for (int m = 0; m < 4; m++)
      af[m] = *(const short8*)&Asm[(wr + m * 16 + c0) * LDA + kof];
#pragma unroll
    for (int n = 0; n < 2; n++) {
      b1f[n] = *(const short8*)&B1sm[(wc + n * 16 + c0) * LDA + kof];
      b3f[n] = *(const short8*)&B3sm[(wc + n * 16 + c0) * LDA + kof];
    }
#pragma unroll
    for (int m = 0; m < 4; m++)
#pragma unroll
      for (int n = 0; n < 2; n++) {
        a1[m][n] = __builtin_amdgcn_mfma_f32_16x16x32_bf16(af[m], b1f[n], a1[m][n], 0, 0, 0);
        a3[m][n] = __builtin_amdgcn_mfma_f32_16x16x32_bf16(af[m], b3f[n], a3[m][n], 0, 0, 0);
      }
  }
  int g = l >> 4;
#pragma unroll
  for (int m = 0; m < 4; m++) {
#pragma unroll
    for (int i = 0; i < 4; i++) {
      int row = bm + wr + m * 16 + g * 4 + i;
#pragma unroll
      for (int n = 0; n < 2; n++) {
        int col = bn + wc + n * 16 + c0;
        float x1 = a1[m][n][i], x3 = a3[m][n][i];
        float sg = x1 / (1.0f + __expf(-x1));
        G[(size_t)row * Nc + col] = f2bf(sg * x3);
      }
    }
  }
}

// ---------------- qkv fp32 [B*N][1536] -> rope'd bf16 q/k + transposed v ----------------
__global__ void prep_qkv(const float* __restrict__ qkv, const float* __restrict__ cosb,
                         const float* __restrict__ sinb, unsigned short* __restrict__ qb,
                         unsigned short* __restrict__ kb, unsigned short* __restrict__ vtb) {
  int n = blockIdx.x, b = blockIdx.y;
  int t = threadIdx.x;
  const float* row = qkv + ((size_t)b * NN + n) * 1536;
  // q: 16 heads * 32 pairs = 512 pairs
#pragma unroll
  for (int p = t; p < 512; p += 256) {
    int head = p >> 5, j = p & 31;
    float xr = row[head * 64 + 2 * j], xi = row[head * 64 + 2 * j + 1];
    float c = cosb[n * 32 + j], s = sinb[n * 32 + j];
    size_t o = (((size_t)(b * NH + head)) * NN + n) * 64 + 2 * j;
    qb[o] = f2bf(xr * c - xi * s);
    qb[o + 1] = f2bf(xr * s + xi * c);
  }
  // k: 4 heads * 32 pairs = 128 pairs
  if (t < 128) {
    int kvh = t >> 5, j = t & 31;
    float xr = row[1024 + kvh * 64 + 2 * j], xi = row[1024 + kvh * 64 + 2 * j + 1];
    float c = cosb[n * 32 + j], s = sinb[n * 32 + j];
    size_t o = (((size_t)(b * NKV + kvh)) * NN + n) * 64 + 2 * j;
    kb[o] = f2bf(xr * c - xi * s);
    kb[o + 1] = f2bf(xr * s + xi * c);
  }
  // v: 4 heads * 64 dims, store transposed [B][NKV][64][N]
  {
    int kvh = t >> 6, d = t & 63;
    float v = row[1280 + kvh * 64 + d];
    vtb[(((size_t)(b * NKV + kvh)) * 64 + d) * NN + n] = f2bf(v);
  }
}

// ---------------- flash attention, causal, GQA (kv head = h % 4 due to jnp.tile) -------
#define LK 72  // padded LDS stride for 64-wide tiles (144B, 16B-aligned)
__global__ __launch_bounds__(256, 2) void attn_k(
    const unsigned short* __restrict__ qb, const unsigned short* __restrict__ kb,
    const unsigned short* __restrict__ vtb, unsigned short* __restrict__ ob) {
  __shared__ __align__(16) unsigned short Ksm[64 * LK];
  __shared__ __align__(16) unsigned short Vsm[64 * LK];
  __shared__ __align__(16) unsigned short Psm[4 * 16 * LK];
  int qt = blockIdx.x, h = blockIdx.y, b = blockIdx.z;
  int kvh = h & 3;  // jnp.tile semantics: head h -> kv head h % NKV
  int tid = threadIdx.x, w = tid >> 6, l = tid & 63;
  int g = l >> 4, c0 = l & 15;

  const unsigned short* qrow_p = qb + (((size_t)(b * NH + h)) * NN + qt * 64 + w * 16 + c0) * 64;
  short8 q0 = *(const short8*)(qrow_p + g * 8);
  short8 q1 = *(const short8*)(qrow_p + 32 + g * 8);
  const unsigned short* Kg = kb + ((size_t)(b * NKV + kvh)) * NN * 64;
  const unsigned short* Vg = vtb + ((size_t)(b * NKV + kvh)) * 64 * NN;

  float m_r[4], l_r[4];
  f32x4 o_r[4] = {};
#pragma unroll
  for (int i = 0; i < 4; i++) { m_r[i] = -1e30f; l_r[i] = 0.0f; }

  int krow = tid >> 3, kch = (tid & 7) * 8;
  int nkt = qt + 1;
  for (int kt = 0; kt < nkt; ++kt) {
    int n0 = kt * 64;
    __syncthreads();
    *(short8*)&Ksm[krow * LK + kch] = *(const short8*)(Kg + (size_t)(n0 + krow) * 64 + kch);
    *(short8*)&Ksm[(krow + 32) * LK + kch] = *(const short8*)(Kg + (size_t)(n0 + krow + 32) * 64 + kch);
    *(short8*)&Vsm[krow * LK + kch] = *(const short8*)(Vg + (size_t)krow * NN + n0 + kch);
    *(short8*)&Vsm[(krow + 32) * LK + kch] = *(const short8*)(Vg + (size_t)(krow + 32) * NN + n0 + kch);
    __syncthreads();
    // S = Q K^T  (16 q-rows x 64 k-cols per wave)
    f32x4 s[4];
#pragma unroll
    for (int sub = 0; sub < 4; sub++) {
      short8 kf0 = *(const short8*)&Ksm[(sub * 16 + c0) * LK + g * 8];
      short8 kf1 = *(const short8*)&Ksm[(sub * 16 + c0) * LK + 32 + g * 8];
      f32x4 a = {0.0f, 0.0f, 0.0f, 0.0f};
      a = __builtin_amdgcn_mfma_f32_16x16x32_bf16(q0, kf0, a, 0, 0, 0);
      a = __builtin_amdgcn_mfma_f32_16x16x32_bf16(q1, kf1, a, 0, 0, 0);
      s[sub] = a;
    }
    bool diag = (kt == qt);
#pragma unroll
    for (int i = 0; i < 4; i++) {
      int qg = qt * 64 + w * 16 + g * 4 + i;
      float sv[4];
#pragma unroll
      for (int sub = 0; sub < 4; sub++) {
        float v = s[sub][i] * 0.125f;
        if (diag && (n0 + sub * 16 + c0 > qg)) v = -1e30f;
        sv[sub] = v;
      }
      float pm = fmaxf(fmaxf(sv[0], sv[1]), fmaxf(sv[2], sv[3]));
#pragma unroll
      for (int o = 1; o < 16; o <<= 1) pm = fmaxf(pm, __shfl_xor(pm, o));
      float mn = fmaxf(m_r[i], pm);
      float alpha = __expf(m_r[i] - mn);
      m_r[i] = mn;
      float rs = 0.0f;
#pragma unroll
      for (int sub = 0; sub < 4; sub++) {
        float p = __expf(sv[sub] - mn);
        rs += p;
        Psm[(w * 16 + g * 4 + i) * LK + sub * 16 + c0] = f2bf(p);
      }
#pragma unroll
      for (int o = 1; o < 16; o <<= 1) rs += __shfl_xor(rs, o);
      l_r[i] = l_r[i] * alpha + rs;
#pragma unroll
      for (int vs = 0; vs < 4; vs++) o_r[vs][i] *= alpha;
    }
    // wave-local P visibility (cross-lane via LDS): drain DS, pin order
    asm volatile("s_waitcnt lgkmcnt(0)" ::: "memory");
    __builtin_amdgcn_sched_barrier(0);
    // O += P @ V
#pragma unroll
    for (int half = 0; half < 2; half++) {
      short8 pa = *(const short8*)&Psm[(w * 16 + c0) * LK + half * 32 + g * 8];
#pragma unroll
      for (int vs = 0; vs < 4; vs++) {
        short8 vf = *(const short8*)&Vsm[(vs * 16 + c0) * LK + half * 32 + g * 8];
        o_r[vs] = __builtin_amdgcn_mfma_f32_16x16x32_bf16(pa, vf, o_r[vs], 0, 0, 0);
      }
    }
  }
#pragma unroll
  for (int i = 0; i < 4; i++) {
    float inv = 1.0f / l_r[i];
    int orow = qt * 64 + w * 16 + g * 4 + i;
    size_t base = ((size_t)b * NN + orow) * 1024 + h * 64;
#pragma unroll
    for (int vs = 0; vs < 4; vs++)
      ob[base + vs * 16 + c0] = f2bf(o_r[vs][i] * inv);
  }
}

// ---------------- launcher ----------------
extern "C" void kernel_launch(void* const* d_in, const int* in_sizes, int n_in,
                              void* d_out, int out_size, void* d_ws, size_t ws_size,
                              hipStream_t stream) {
  (void)in_sizes; (void)n_in; (void)out_size; (void)ws_size;
  const float* x    = (const float*)d_in[0];
  const float* w_an = (const float*)d_in[1];
  const float* w_fn = (const float*)d_in[2];
  const float* Wq   = (const float*)d_in[3];
  const float* Wkv  = (const float*)d_in[4];
  const float* Wo   = (const float*)d_in[5];
  const float* W1   = (const float*)d_in[6];
  const float* W2   = (const float*)d_in[7];
  const float* W3   = (const float*)d_in[8];
  const float* cosb = (const float*)d_in[9];
  const float* sinb = (const float*)d_in[10];
  float* out = (float*)d_out;

  char* ws = (char*)d_ws;
  size_t off = 0;
  auto take = [&](size_t bytes) {
    size_t r = off;
    off += (bytes + 255) & ~(size_t)255;
    return r;
  };
  unsigned short* WqkvT = (unsigned short*)(ws + take((size_t)1536 * 1024 * 2));
  unsigned short* WoT   = (unsigned short*)(ws + take((size_t)1024 * 1024 * 2));
  unsigned short* W1T   = (unsigned short*)(ws + take((size_t)2688 * 1024 * 2));
  unsigned short* W3T   = (unsigned short*)(ws + take((size_t)2688 * 1024 * 2));
  unsigned short* W2T   = (unsigned short*)(ws + take((size_t)2688 * 1024 * 2));
  unsigned short* hA    = (unsigned short*)(ws + take((size_t)MM * DIM * 2));  // reused as h2
  char* qkv_region = ws + take((size_t)MM * 1536 * 4);  // reused as g (22.0MB <= 25.2MB)
  float* qkv = (float*)qkv_region;
  unsigned short* gbuf = (unsigned short*)qkv_region;
  unsigned short* qbuf = (unsigned short*)(ws + take((size_t)MM * DIM * 2));
  unsigned short* kbuf = (unsigned short*)(ws + take((size_t)BB * NKV * NN * HD * 2));
  unsigned short* vtb  = (unsigned short*)(ws + take((size_t)BB * NKV * NN * HD * 2));
  unsigned short* obuf = (unsigned short*)(ws + take((size_t)MM * DIM * 2));
  float* x2 = (float*)(ws + take((size_t)MM * DIM * 4));

  // weight transposes (bf16)
  transpose_k<<<dim3(1024 / 32, 1024 / 32), 256, 0, stream>>>(Wq, WqkvT, 1024, 1024);
  transpose_k<<<dim3(512 / 32, 1024 / 32), 256, 0, stream>>>(Wkv, WqkvT + (size_t)1024 * 1024, 1024, 512);
  transpose_k<<<dim3(1024 / 32, 1024 / 32), 256, 0, stream>>>(Wo, WoT, 1024, 1024);
  transpose_k<<<dim3(2688 / 32, 1024 / 32), 256, 0, stream>>>(W1, W1T, 1024, 2688);
  transpose_k<<<dim3(2688 / 32, 1024 / 32), 256, 0, stream>>>(W3, W3T, 1024, 2688);
  transpose_k<<<dim3(1024 / 32, 2688 / 32), 256, 0, stream>>>(W2, W2T, 2688, 1024);

  // attn norm
  rmsnorm_k<<<MM, 256, 0, stream>>>(x, w_an, hA);
  // qkv projection (fused q+kv): [4096][1536]
  gemm_f32<false><<<dim3(1536 / 128, MM / 128), 256, 0, stream>>>(hA, WqkvT, nullptr, qkv, 1536, 1024);
  // rope + layout
  prep_qkv<<<dim3(NN, BB), 256, 0, stream>>>(qkv, cosb, sinb, qbuf, kbuf, vtb);
  // attention
  attn_k<<<dim3(NN / 64, NH, BB), 256, 0, stream>>>(qbuf, kbuf, vtb, obuf);
  // x2 = x + o @ Wo
  gemm_f32<true><<<dim3(1024 / 128, MM / 128), 256, 0, stream>>>(obuf, WoT, x, x2, 1024, 1024);
  // ffn norm (h2 in hA slot)
  rmsnorm_k<<<MM, 256, 0, stream>>>(x2, w_fn, hA);
  // g = silu(h2@W1) * (h2@W3)
  gemm_ffn13<<<dim3(INTER / 64, MM / 128), 256, 0, stream>>>(hA, W1T, W3T, gbuf, INTER, 1024);
  // out = x2 + g @ W2
  gemm_f32<true><<<dim3(1024 / 128, MM / 128), 256, 0, stream>>>(gbuf, W2T, x2, out, 1024, 2688);
}